// Round 3
// baseline (137.639 us; speedup 1.0000x reference)
//
#include <hip/hip_runtime.h>

#define MARGIN1 0.5f
#define MARGIN2 1.0f

// ws layout (floats): ws_f[0] = ticket counter (int), partials at
// ws_f[16 + bid*16] (64-byte padded entries -> no cross-XCD false sharing).

__global__ void soso_zero_kernel(int* __restrict__ counter) {
    if (threadIdx.x == 0) *counter = 0;
}

// One wave (64 lanes) per 2 CONSECUTIVE groups of 3 rows (12 KB contiguous).
// Lane l covers floats [4l,4l+4) and [256+4l,256+4l+4) of each 512-float row
// -> 6 coalesced float4 loads per group. Row sums via 6-step 64-lane
// butterfly. Block partial -> padded slot; ticket counter (agent scope);
// last-finishing block reduces all partials in fixed order (bit-deterministic)
// and writes the mean. No separate reduce kernel, no memset nodes.
__global__ __launch_bounds__(256, 8) void soso_main_kernel(
    const int* __restrict__ lab,
    const float* __restrict__ emb,
    const float* __restrict__ proto,
    float* __restrict__ out,
    float* __restrict__ partial,   // padded: entry i at partial[i*16]
    int* __restrict__ counter,
    int ngroups,
    float inv_count,
    int nblocks)
{
    const int lane  = threadIdx.x & 63;
    const int wid   = threadIdx.x >> 6;           // 0..3
    const int gwave = blockIdx.x * 4 + wid;
    const int g0    = gwave * 2;                  // 2 consecutive groups

    const float4 p0 = *reinterpret_cast<const float4*>(proto + 4 * lane);
    const float4 p1 = *reinterpret_cast<const float4*>(proto + 256 + 4 * lane);

    float acc = 0.0f;

#pragma unroll
    for (int gg = 0; gg < 2; ++gg) {
        const int g = g0 + gg;
        if (g < ngroups) {
            const float* base = emb + (size_t)g * 1536u;   // 3 rows * 512
            float ds[3];
#pragma unroll
            for (int r = 0; r < 3; ++r) {
                const float* row = base + r * 512;
                const float4 e0 = *reinterpret_cast<const float4*>(row + 4 * lane);
                const float4 e1 = *reinterpret_cast<const float4*>(row + 256 + 4 * lane);
                float s = 0.0f, t;
                t = p0.x - e0.x; s = fmaf(t, t, s);
                t = p0.y - e0.y; s = fmaf(t, t, s);
                t = p0.z - e0.z; s = fmaf(t, t, s);
                t = p0.w - e0.w; s = fmaf(t, t, s);
                t = p1.x - e1.x; s = fmaf(t, t, s);
                t = p1.y - e1.y; s = fmaf(t, t, s);
                t = p1.z - e1.z; s = fmaf(t, t, s);
                t = p1.w - e1.w; s = fmaf(t, t, s);
#pragma unroll
                for (int off = 32; off > 0; off >>= 1)
                    s += __shfl_xor(s, off, 64);
                ds[r] = s;
            }
            const int l0 = lab[3 * g + 0];
            const int l1 = lab[3 * g + 1];
            const float d1 = (l0 == 0) ? ds[0] : (l1 == 0) ? ds[1] : ds[2];
            const float d2 = (l0 == 1) ? ds[0] : (l1 == 1) ? ds[1] : ds[2];
            const float d3 = (l0 == 2) ? ds[0] : (l1 == 2) ? ds[1] : ds[2];

            acc += fmaxf(d1 - d2 + MARGIN1, 0.0f)
                 + fmaxf(d2 - d3 + MARGIN1, 0.0f)
                 + fmaxf(d1 - d3 + MARGIN2, 0.0f);
        }
    }

    // Combine the block's 4 waves.
    __shared__ float smem[4];
    __shared__ int isLast;
    if (lane == 0) smem[wid] = acc;
    __syncthreads();
    if (threadIdx.x == 0) {
        const float blockSum = smem[0] + smem[1] + smem[2] + smem[3];
        // Release-store the padded partial at the coherent (agent) scope,
        // then bump the ticket. The block that completes the count inherits
        // visibility of all prior partials (acq_rel RMW chain).
        __hip_atomic_store(&partial[(size_t)blockIdx.x * 16], blockSum,
                           __ATOMIC_RELEASE, __HIP_MEMORY_SCOPE_AGENT);
        const int old = __hip_atomic_fetch_add(counter, 1,
                           __ATOMIC_ACQ_REL, __HIP_MEMORY_SCOPE_AGENT);
        isLast = (old == nblocks - 1);
    }
    __syncthreads();

    if (isLast) {
        // Fixed-order reduction -> bit-deterministic across replays.
        float s = 0.0f;
        for (int i = threadIdx.x; i < nblocks; i += 256)
            s += __hip_atomic_load(&partial[(size_t)i * 16],
                                   __ATOMIC_ACQUIRE, __HIP_MEMORY_SCOPE_AGENT);
#pragma unroll
        for (int off = 32; off > 0; off >>= 1)
            s += __shfl_xor(s, off, 64);
        if (lane == 0) smem[wid] = s;
        __syncthreads();
        if (threadIdx.x == 0)
            out[0] = (smem[0] + smem[1] + smem[2] + smem[3]) * inv_count;
    }
}

extern "C" void kernel_launch(void* const* d_in, const int* in_sizes, int n_in,
                              void* d_out, int out_size, void* d_ws, size_t ws_size,
                              hipStream_t stream)
{
    const int*   lab   = (const int*)d_in[0];    // true_label [B] int32
    const float* emb   = (const float*)d_in[1];  // embedding  [B,512] f32
    const float* proto = (const float*)d_in[2];  // proto      [512]   f32
    float* out = (float*)d_out;

    const int B = in_sizes[0];
    const int ngroups = B / 3;                         // 16384
    const int waves   = (ngroups + 1) / 2;             // 2 groups per wave
    const int blocks  = (waves + 3) / 4;               // 2048

    float* ws_f    = (float*)d_ws;
    int*   counter = (int*)ws_f;                       // ws_f[0]
    float* partial = ws_f + 16;                        // padded entries, 16 floats apart

    soso_zero_kernel<<<1, 64, 0, stream>>>(counter);
    soso_main_kernel<<<blocks, 256, 0, stream>>>(lab, emb, proto, out,
                                                 partial, counter,
                                                 ngroups, 1.0f / (float)ngroups,
                                                 blocks);
}

// Round 4
// 23.139 us; speedup vs baseline: 5.9483x; 5.9483x over previous
//
#include <hip/hip_runtime.h>

#define MARGIN1 0.5f
#define MARGIN2 1.0f

// Kernel 1: one wave (64 lanes) per 2 CONSECUTIVE groups of 3 rows
// (12 KB contiguous per wave). Lane l covers floats [4l,4l+4) and
// [256+4l,256+4l+4) of each 512-float row -> 6 coalesced float4 loads per
// group, all issued before the reduction. The three row-sums are reduced
// together in one 6-step butterfly (3 independent shuffles per step -> ILP
// hides DS latency). Block partial written with a plain store; the kernel
// boundary provides cross-XCD visibility (no agent-scope fences -- round 3
// showed per-block release/acquire costs ~180 us in L2 flushes).
__global__ __launch_bounds__(256, 8) void soso_main_kernel(
    const int* __restrict__ lab,
    const float* __restrict__ emb,
    const float* __restrict__ proto,
    float* __restrict__ partial,
    int ngroups)
{
    const int lane  = threadIdx.x & 63;
    const int wid   = threadIdx.x >> 6;           // 0..3
    const int gwave = blockIdx.x * 4 + wid;
    const int g0    = gwave * 2;                  // 2 consecutive groups

    const float4 p0 = *reinterpret_cast<const float4*>(proto + 4 * lane);
    const float4 p1 = *reinterpret_cast<const float4*>(proto + 256 + 4 * lane);

    float acc = 0.0f;

#pragma unroll
    for (int gg = 0; gg < 2; ++gg) {
        const int g = g0 + gg;
        if (g < ngroups) {
            const float* base = emb + (size_t)g * 1536u;   // 3 rows * 512

            // Issue all 6 loads for the group's 3 rows up front.
            float4 e0[3], e1[3];
#pragma unroll
            for (int r = 0; r < 3; ++r) {
                const float* row = base + r * 512;
                e0[r] = *reinterpret_cast<const float4*>(row + 4 * lane);
                e1[r] = *reinterpret_cast<const float4*>(row + 256 + 4 * lane);
            }

            // Per-lane partial sums for the 3 rows.
            float s[3];
#pragma unroll
            for (int r = 0; r < 3; ++r) {
                float v = 0.0f, t;
                t = p0.x - e0[r].x; v = fmaf(t, t, v);
                t = p0.y - e0[r].y; v = fmaf(t, t, v);
                t = p0.z - e0[r].z; v = fmaf(t, t, v);
                t = p0.w - e0[r].w; v = fmaf(t, t, v);
                t = p1.x - e1[r].x; v = fmaf(t, t, v);
                t = p1.y - e1[r].y; v = fmaf(t, t, v);
                t = p1.z - e1[r].z; v = fmaf(t, t, v);
                t = p1.w - e1[r].w; v = fmaf(t, t, v);
                s[r] = v;
            }

            // 6-step butterfly over all 3 rows at once (3-wide ILP per step).
#pragma unroll
            for (int off = 32; off > 0; off >>= 1) {
                const float t0 = __shfl_xor(s[0], off, 64);
                const float t1 = __shfl_xor(s[1], off, 64);
                const float t2 = __shfl_xor(s[2], off, 64);
                s[0] += t0; s[1] += t1; s[2] += t2;
            }

            // Wave-uniform label reads; branchless map label->distance.
            const int l0 = lab[3 * g + 0];
            const int l1 = lab[3 * g + 1];
            const float d1 = (l0 == 0) ? s[0] : (l1 == 0) ? s[1] : s[2];
            const float d2 = (l0 == 1) ? s[0] : (l1 == 1) ? s[1] : s[2];
            const float d3 = (l0 == 2) ? s[0] : (l1 == 2) ? s[1] : s[2];

            acc += fmaxf(d1 - d2 + MARGIN1, 0.0f)
                 + fmaxf(d2 - d3 + MARGIN1, 0.0f)
                 + fmaxf(d1 - d3 + MARGIN2, 0.0f);
        }
    }

    // acc is wave-uniform; combine the block's 4 waves via LDS, plain store.
    __shared__ float smem[4];
    if (lane == 0) smem[wid] = acc;
    __syncthreads();
    if (threadIdx.x == 0)
        partial[blockIdx.x] = smem[0] + smem[1] + smem[2] + smem[3];
}

// Kernel 2: deterministic single-block reduction of per-block partials.
__global__ __launch_bounds__(256) void soso_reduce_kernel(
    const float* __restrict__ partial,
    float* __restrict__ out,
    int n,
    float inv_count)
{
    float s = 0.0f;
    for (int i = threadIdx.x; i < n; i += 256)
        s += partial[i];
#pragma unroll
    for (int off = 32; off > 0; off >>= 1)
        s += __shfl_xor(s, off, 64);
    __shared__ float smem[4];
    if ((threadIdx.x & 63) == 0) smem[threadIdx.x >> 6] = s;
    __syncthreads();
    if (threadIdx.x == 0)
        out[0] = (smem[0] + smem[1] + smem[2] + smem[3]) * inv_count;
}

extern "C" void kernel_launch(void* const* d_in, const int* in_sizes, int n_in,
                              void* d_out, int out_size, void* d_ws, size_t ws_size,
                              hipStream_t stream)
{
    const int*   lab   = (const int*)d_in[0];    // true_label [B] int32
    const float* emb   = (const float*)d_in[1];  // embedding  [B,512] f32
    const float* proto = (const float*)d_in[2];  // proto      [512]   f32
    float* out = (float*)d_out;

    const int B = in_sizes[0];
    const int ngroups = B / 3;                         // 16384
    const int waves   = (ngroups + 1) / 2;             // 2 groups per wave
    const int blocks  = (waves + 3) / 4;               // 2048

    float* partial = (float*)d_ws;                     // 2048 floats scratch

    soso_main_kernel<<<blocks, 256, 0, stream>>>(lab, emb, proto, partial, ngroups);
    soso_reduce_kernel<<<1, 256, 0, stream>>>(partial, out, blocks,
                                              1.0f / (float)ngroups);
}